// Round 8
// baseline (136.446 us; speedup 1.0000x reference)
//
#include <hip/hip_runtime.h>

#define B_ 32
#define C_ 64          // Cin = Cout
#define H_ 112
#define W_ 112
#define HW (H_ * W_)
#define HTILES 56            // 2-row tiles per image
#define NBLKC (B_ * HTILES)  // 1792, %8==0 for XCD swizzle

#define SLOTS 114            // slot = w+1; slots 0,113 are zeros
#define HCH 64               // bytes per (h,half,slot): 32 cin bf16
#define XHROWB (SLOTS * HCH)               // 7296 B per (b,h,half)
#define XROWB (2 * XHROWB)                 // 14592 B per (b,h)
#define XT_BYTES ((size_t)B_ * H_ * XROWB) // ~52.3 MB
#define WQ_OFF 131072
// xs: 4 row-slots of 7296 B; last row +1024 B overhang so pad-frag reads
// (slot up to 129, discarded results) stay inside the allocation.
#define XS_BYTES (4 * XHROWB + 1024)       // 30208

typedef short bf16x8 __attribute__((ext_vector_type(8)));
typedef float f32x4 __attribute__((ext_vector_type(4)));
typedef unsigned int u32;

#define GLOAD_LDS(g, l, sz)                                                   \
    __builtin_amdgcn_global_load_lds(                                         \
        (const __attribute__((address_space(1))) u32*)(const void*)(g),       \
        (__attribute__((address_space(3))) u32*)(void*)(l), (sz), 0, 0)

__device__ inline unsigned short f2bf(float f) {
    union { float f; unsigned u; } v;
    v.f = f;
    unsigned u = v.u;
    u += 0x7fffu + ((u >> 16) & 1u);   // RNE
    return (unsigned short)(u >> 16);
}

// ---------------------------------------------------------------------------
// Transform: x[b][c][h][w] fp32 -> xt[b][h][half][slot][32cin] bf16 with
// full-row XOR swizzle: phys = L ^ (((L>>6)&7)<<4), L = slot*64 + cpl*4.
// Bijective (bit6 recoverable from bit8); reader applies the same map.
// First 144 blocks also quantize w -> wq (folds the quant_w launch).
// ---------------------------------------------------------------------------
__global__ __launch_bounds__(256) void xform(const float* __restrict__ x,
                                             unsigned short* __restrict__ xt,
                                             const float* __restrict__ w,
                                             unsigned short* __restrict__ wq) {
    __shared__ unsigned short pl[C_ * SLOTS];

    const int tid = threadIdx.x;
    const int b   = blockIdx.x / H_;
    const int h   = blockIdx.x % H_;

#pragma unroll
    for (int it = 0; it < 7; ++it) {
        const int u  = tid + 256 * it;        // < 1792 = 64c * 28 quads
        const int c  = u / 28;
        const int w4 = u % 28;
        const f32x4 v =
            *(const f32x4*)(x + ((size_t)(b * C_ + c) * H_ + h) * W_ + w4 * 4);
        const u32 lo = (u32)f2bf(v[0]) | ((u32)f2bf(v[1]) << 16);
        const u32 hi = (u32)f2bf(v[2]) | ((u32)f2bf(v[3]) << 16);
        u32* p = (u32*)&pl[c * SLOTS + w4 * 4];
        p[0] = lo;
        p[1] = hi;
    }
    __syncthreads();

    char* xtrow = (char*)xt + (size_t)(b * H_ + h) * XROWB;
#pragma unroll
    for (int it = 0; it < 15; ++it) {
        const int u = tid + 256 * it;         // < 3648 = 114 slots * 32 cps
        if (u < SLOTS * 32) {
            const int slot = u >> 5;
            const int cp   = u & 31;          // global cin pair
            const int half = cp >> 4;
            const int cpl  = cp & 15;
            u32 val = 0;
            if (1 <= slot && slot <= 112) {
                const int ww = slot - 1;
                val = (u32)pl[(2 * cp) * SLOTS + ww] |
                      ((u32)pl[(2 * cp + 1) * SLOTS + ww] << 16);
            }
            const int L = slot * 64 + cpl * 4;
            *(u32*)(xtrow + half * XHROWB + (L ^ (((L >> 6) & 7) << 4))) = val;
        }
    }

    // folded weight quantization: w[co][cin][kh][kw] -> wq[shift][co][cin]
    if (blockIdx.x < 144) {
        const int i = blockIdx.x * 256 + tid;   // < 36864 = C_*C_*9
        const int k   = i % 9;
        const int cin = (i / 9) % C_;
        const int co  = i / (9 * C_);
        const float v = w[i];
        const float q = (v > 0.f) ? 1.f : ((v < 0.f) ? -1.f : 0.f);
        wq[(k * C_ + co) * C_ + cin] = f2bf(q);
    }
}

// ---------------------------------------------------------------------------
// Conv implicit GEMM. Block = (b, 2 output rows); grid 1792; 4 blocks/CU.
// Two cin-half phases (LDS 30 KB). STATIC F=4 wave split over 16 padded
// N-frags (2 rows x 8 colgroups): wave w owns nf = 4w..4w+3; acc[4][4]
// statically indexed, no runtime guards. nfc==7 is padding: its B-reads hit
// the LDS overhang (junk), its acc is never stored.
// ---------------------------------------------------------------------------
__global__ __launch_bounds__(256, 4) void conv_mfma(
    const unsigned short* __restrict__ xt, const unsigned short* __restrict__ wq,
    const float* __restrict__ bias, const float* __restrict__ scale,
    float* __restrict__ out) {
    __shared__ char xs[XS_BYTES];

    const int tid  = threadIdx.x;
    const int lane = tid & 63;
    const int wave = tid >> 6;
    const int lcol = lane & 15;
    const int kg   = lane >> 4;
    const int rowo = wave >> 1;        // output row this wave computes
    const int cgrp = wave & 1;         // colgroup half: nfc = cgrp*4 + i

    const int bid = blockIdx.x;
    const int s   = (bid & 7) * (NBLKC / 8) + (bid >> 3);   // XCD-bijective
    const int b   = s / HTILES;
    const int h0  = (s % HTILES) * 2;

    const char* xtc = (const char*)xt + (size_t)b * H_ * XROWB;

    // precomputed swizzled B-frag offsets within a row-half [dw][i]
    int boff[3][4];
#pragma unroll
    for (int dw = 0; dw < 3; ++dw)
#pragma unroll
        for (int i = 0; i < 4; ++i) {
            const int slot = (cgrp * 4 + i) * 16 + lcol + dw;
            const int L    = slot * 64 + kg * 16;
            boff[dw][i]    = L ^ (((L >> 6) & 7) << 4);
        }

    f32x4 acc[4][4];   // [i (nf)][m (cout frag)] -- fully static
#pragma unroll
    for (int i = 0; i < 4; ++i)
#pragma unroll
        for (int m = 0; m < 4; ++m) acc[i][m] = (f32x4){0.f, 0.f, 0.f, 0.f};

    const int xrow = h0 - 1 + wave;    // row this wave stages
    const bool inb = (0 <= xrow) && (xrow < H_);
    char* dst = xs + wave * XHROWB;

#pragma unroll
    for (int ph = 0; ph < 2; ++ph) {
        if (ph) __syncthreads();   // phase-0 reads done before overwrite

        // ---- stage: wave r copies x-row h0-1+r, cin-half ph (7296 B) ----
        if (inb) {
            const char* src = xtc + (size_t)xrow * XROWB + ph * XHROWB;
#pragma unroll
            for (int ch = 0; ch < 7; ++ch)
                GLOAD_LDS(src + ch * 1024 + lane * 16,
                          dst + ch * 1024 + lane * 16, 16);
            if (lane < 32)   // tail 128 B
                GLOAD_LDS(src + 7168 + lane * 4, dst + 7168 + lane * 4, 4);
        } else if (ph == 0) {      // zero once; never overwritten after
            char* d = dst + lane * 16;
            const f32x4 z = {0.f, 0.f, 0.f, 0.f};
#pragma unroll
            for (int ch = 0; ch < 7; ++ch) *(f32x4*)(d + ch * 1024) = z;
            if (lane < 32) *(u32*)(dst + 7168 + lane * 4) = 0u;
        }
        __syncthreads();

        const unsigned short* wqp = wq + lcol * C_ + ph * 32 + kg * 8;

#pragma unroll
        for (int dh = 0; dh < 3; ++dh) {
            const char* rowb = xs + (rowo + dh) * XHROWB;
#pragma unroll
            for (int dw = 0; dw < 3; ++dw) {
                const unsigned short* wsft = wqp + (dh * 3 + dw) * (C_ * C_);
                bf16x8 af[4];
#pragma unroll
                for (int m = 0; m < 4; ++m)
                    af[m] = *(const bf16x8*)(wsft + m * 16 * C_);
#pragma unroll
                for (int i = 0; i < 4; ++i) {
                    const bf16x8 bv = *(const bf16x8*)(rowb + boff[dw][i]);
#pragma unroll
                    for (int m = 0; m < 4; ++m)
                        acc[i][m] = __builtin_amdgcn_mfma_f32_16x16x32_bf16(
                            af[m], bv, acc[i][m], 0, 0, 0);
                }
            }
        }
    }

    // ---- epilogue: skip the padding colgroup (nfc == 7) ----
    const float sc = scale[0];
    const int h = h0 + rowo;
#pragma unroll
    for (int i = 0; i < 4; ++i) {
        const int nfc = cgrp * 4 + i;
        if (nfc < 7) {                 // wave-uniform; false only for nf pad
            const int col = nfc * 16 + lcol;
#pragma unroll
            for (int m = 0; m < 4; ++m) {
                const int cobase = m * 16 + kg * 4;
                const f32x4 bs = *(const f32x4*)(bias + cobase);
#pragma unroll
                for (int rr = 0; rr < 4; ++rr)
                    out[((size_t)(b * C_ + cobase + rr)) * HW + h * W_ + col] =
                        sc * (acc[i][m][rr] + bs[rr]);
            }
        }
    }
}

extern "C" void kernel_launch(void* const* d_in, const int* in_sizes, int n_in,
                              void* d_out, int out_size, void* d_ws,
                              size_t ws_size, hipStream_t stream) {
    const float* x     = (const float*)d_in[0];
    const float* w     = (const float*)d_in[1];
    const float* bias  = (const float*)d_in[2];
    const float* scale = (const float*)d_in[3];
    float* out         = (float*)d_out;

    unsigned short* wq = (unsigned short*)d_ws;   // 73728 B
    unsigned short* xt = (unsigned short*)((char*)d_ws + WQ_OFF);

    xform<<<B_ * H_, 256, 0, stream>>>(x, xt, w, wq);
    conv_mfma<<<NBLKC, 256, 0, stream>>>(xt, wq, bias, scale, out);
}

// Round 9
// 116.637 us; speedup vs baseline: 1.1698x; 1.1698x over previous
//
#include <hip/hip_runtime.h>

#define B_ 32
#define C_ 64          // Cin = Cout
#define H_ 112
#define W_ 112
#define HW (H_ * W_)
#define HTILES 56            // 2-row tiles per image
#define NBLKC (B_ * HTILES)  // 1792, %8==0 for XCD swizzle

#define SLOTS 114            // slot = w+1; slots 0,113 are zeros
#define CHUNK 128            // bytes per (h,slot): 64 cin bf16
#define XROWB (SLOTS * CHUNK)              // 14592 B per (b,h)
#define XT_BYTES ((size_t)B_ * H_ * XROWB) // ~52.3 MB
#define WQ_OFF 131072

typedef short bf16x8 __attribute__((ext_vector_type(8)));
typedef float f32x4 __attribute__((ext_vector_type(4)));
typedef unsigned int u32;

#define GLOAD_LDS(g, l, sz)                                                   \
    __builtin_amdgcn_global_load_lds(                                         \
        (const __attribute__((address_space(1))) u32*)(const void*)(g),       \
        (__attribute__((address_space(3))) u32*)(void*)(l), (sz), 0, 0)

__device__ inline unsigned short f2bf(float f) {
    union { float f; unsigned u; } v;
    v.f = f;
    unsigned u = v.u;
    u += 0x7fffu + ((u >> 16) & 1u);   // RNE
    return (unsigned short)(u >> 16);
}

// ---------------------------------------------------------------------------
// Transform (VERIFIED rounds 4-6, runs at HBM floor):
// x[b][c][h][w] fp32 -> xt[b][h][slot][cin] bf16; within each 128-B chunk
// the dword for cin-pair cp lives at (cp*4)^((slot&7)<<4).
// First 144 blocks also quantize w -> wq[shift][co][cin] (fold verified r8).
// ---------------------------------------------------------------------------
__global__ __launch_bounds__(256) void xform(const float* __restrict__ x,
                                             unsigned short* __restrict__ xt,
                                             const float* __restrict__ w,
                                             unsigned short* __restrict__ wq) {
    __shared__ unsigned short pl[C_ * SLOTS];

    const int tid = threadIdx.x;
    const int b   = blockIdx.x / H_;
    const int h   = blockIdx.x % H_;

#pragma unroll
    for (int it = 0; it < 7; ++it) {
        const int u  = tid + 256 * it;        // < 1792 = 64c * 28 quads
        const int c  = u / 28;
        const int w4 = u % 28;
        const f32x4 v =
            *(const f32x4*)(x + ((size_t)(b * C_ + c) * H_ + h) * W_ + w4 * 4);
        const u32 lo = (u32)f2bf(v[0]) | ((u32)f2bf(v[1]) << 16);
        const u32 hi = (u32)f2bf(v[2]) | ((u32)f2bf(v[3]) << 16);
        u32* p = (u32*)&pl[c * SLOTS + w4 * 4];
        p[0] = lo;
        p[1] = hi;
    }
    __syncthreads();

    unsigned short* xtrow = xt + (size_t)(b * H_ + h) * (XROWB / 2);
#pragma unroll
    for (int it = 0; it < 15; ++it) {
        const int u = tid + 256 * it;         // < 3648 = 114 slots * 32 cps
        if (u < SLOTS * 32) {
            const int slot = u >> 5;
            const int cp   = u & 31;
            u32 val = 0;
            if (1 <= slot && slot <= 112) {
                const int ww = slot - 1;
                val = (u32)pl[(2 * cp) * SLOTS + ww] |
                      ((u32)pl[(2 * cp + 1) * SLOTS + ww] << 16);
            }
            *(u32*)((char*)xtrow + slot * CHUNK +
                    ((cp * 4) ^ ((slot & 7) << 4))) = val;
        }
    }

    // folded weight quantization
    if (blockIdx.x < 144) {
        const int i   = blockIdx.x * 256 + tid;   // < 36864 = C_*C_*9
        const int k   = i % 9;
        const int cin = (i / 9) % C_;
        const int co  = i / (9 * C_);
        const float v = w[i];
        const float q = (v > 0.f) ? 1.f : ((v < 0.f) ? -1.f : 0.f);
        wq[(k * C_ + co) * C_ + cin] = f2bf(q);
    }
}

// ---------------------------------------------------------------------------
// Conv implicit GEMM = round-4 staging/layout + round-6 F=4 mapping.
// Block = (b, 2 output rows); stages xt rows h0-1..h0+2 linearly (58368 B)
// via global_load_lds. Wave handles nf = wave+4i (14 N-frags, guard nf<14),
// ALL 64 couts: each ds_read_b128 B-frag feeds 4 MFMAs.
// Block totals: 252 ds_read_b128, 1008 MFMA. Conflict-free (measured r4/r6).
// ---------------------------------------------------------------------------
__global__ __launch_bounds__(256) void conv_mfma(
    const unsigned short* __restrict__ xt, const unsigned short* __restrict__ wq,
    const float* __restrict__ bias, const float* __restrict__ scale,
    float* __restrict__ out) {
    __shared__ char xs[4 * XROWB];   // 58368 B

    const int tid  = threadIdx.x;
    const int lane = tid & 63;
    const int wave = tid >> 6;
    const int lcol = lane & 15;
    const int kg   = lane >> 4;

    const int bid = blockIdx.x;
    const int s   = (bid & 7) * (NBLKC / 8) + (bid >> 3);   // XCD-bijective
    const int b   = s / HTILES;
    const int h0  = (s % HTILES) * 2;

    const char* xtc = (const char*)xt + (size_t)b * H_ * XROWB;

    // ---- stage: wave r copies xt row h0-1+r linearly into LDS (round 4) ----
    {
        const int r    = wave;
        const int xrow = h0 - 1 + r;
        char* dst = xs + r * XROWB;
        if (0 <= xrow && xrow < H_) {
            const char* src = xtc + (size_t)xrow * XROWB + lane * 16;
#pragma unroll
            for (int ch = 0; ch < 14; ++ch)
                GLOAD_LDS(src + ch * 1024, dst + ch * 1024, 16);
            GLOAD_LDS(xtc + (size_t)xrow * XROWB + 14336 + lane * 4,
                      dst + 14336, 4);
        } else {
            char* d = dst + lane * 16;
            const f32x4 z = {0.f, 0.f, 0.f, 0.f};
#pragma unroll
            for (int ch = 0; ch < 14; ++ch) *(f32x4*)(d + ch * 1024) = z;
            *(u32*)(dst + 14336 + lane * 4) = 0u;
        }
    }
    __syncthreads();

    // swizzle-adjusted K-offsets (verified round 4)
    int koff[3][2];
#pragma unroll
    for (int dw = 0; dw < 3; ++dw) {
        const int key = ((lcol + dw) & 7) << 4;
        koff[dw][0] = (kg * 16) ^ key;
        koff[dw][1] = (64 + kg * 16) ^ key;
    }

    f32x4 acc[4][4];   // [i (nf slot)][m (cout frag)]
#pragma unroll
    for (int i = 0; i < 4; ++i)
#pragma unroll
        for (int m = 0; m < 4; ++m) acc[i][m] = (f32x4){0.f, 0.f, 0.f, 0.f};

    const unsigned short* wqa = wq + lcol * C_ + kg * 8;

#pragma unroll
    for (int dh = 0; dh < 3; ++dh) {
#pragma unroll
        for (int dw = 0; dw < 3; ++dw) {
            const unsigned short* wsft = wqa + (dh * 3 + dw) * (C_ * C_);
#pragma unroll
            for (int c0 = 0; c0 < 2; ++c0) {
                bf16x8 af[4];
#pragma unroll
                for (int m = 0; m < 4; ++m)
                    af[m] = *(const bf16x8*)(wsft + m * 16 * C_ + c0 * 32);
#pragma unroll
                for (int i = 0; i < 4; ++i) {
                    const int nf = wave + 4 * i;
                    if (nf < 14) {                     // wave-uniform guard
                        const int nfr  = (nf >= 7) ? 1 : 0;
                        const int nfc  = nf - 7 * nfr;
                        const int slot = nfc * 16 + lcol + dw;
                        const bf16x8 bv = *(const bf16x8*)(
                            xs + (nfr + dh) * XROWB + slot * CHUNK +
                            koff[dw][c0]);
#pragma unroll
                        for (int m = 0; m < 4; ++m)
                            acc[i][m] =
                                __builtin_amdgcn_mfma_f32_16x16x32_bf16(
                                    af[m], bv, acc[i][m], 0, 0, 0);
                    }
                }
            }
        }
    }

    // ---- epilogue ----
    const float sc = scale[0];
#pragma unroll
    for (int i = 0; i < 4; ++i) {
        const int nf = wave + 4 * i;
        if (nf < 14) {
            const int nfr = (nf >= 7) ? 1 : 0;
            const int nfc = nf - 7 * nfr;
            const int h   = h0 + nfr;
            const int col = nfc * 16 + lcol;
#pragma unroll
            for (int m = 0; m < 4; ++m) {
                const int cobase = m * 16 + kg * 4;
                const f32x4 bs = *(const f32x4*)(bias + cobase);
#pragma unroll
                for (int rr = 0; rr < 4; ++rr)
                    out[((size_t)(b * C_ + cobase + rr)) * HW + h * W_ + col] =
                        sc * (acc[i][m][rr] + bs[rr]);
            }
        }
    }
}

extern "C" void kernel_launch(void* const* d_in, const int* in_sizes, int n_in,
                              void* d_out, int out_size, void* d_ws,
                              size_t ws_size, hipStream_t stream) {
    const float* x     = (const float*)d_in[0];
    const float* w     = (const float*)d_in[1];
    const float* bias  = (const float*)d_in[2];
    const float* scale = (const float*)d_in[3];
    float* out         = (float*)d_out;

    unsigned short* wq = (unsigned short*)d_ws;   // 73728 B
    unsigned short* xt = (unsigned short*)((char*)d_ws + WQ_OFF);

    xform<<<B_ * H_, 256, 0, stream>>>(x, xt, w, wq);
    conv_mfma<<<NBLKC, 256, 0, stream>>>(xt, wq, bias, scale, out);
}

// Round 10
// 63.655 us; speedup vs baseline: 2.1435x; 1.8323x over previous
//
#include <hip/hip_runtime.h>

#define B_ 32
#define C_ 64          // Cin = Cout
#define H_ 112
#define W_ 112
#define HW (H_ * W_)
#define HTILES 56            // 2-row tiles per image
#define NBLKC (B_ * HTILES)  // 1792, %8==0 for XCD swizzle

#define SLOTS 114            // slot = w+1; slots 0,113 are zeros
#define CHUNK 128            // bytes per (h,slot): 64 cin bf16
#define XROWB (SLOTS * CHUNK)              // 14592 B per (b,h)
#define XT_BYTES ((size_t)B_ * H_ * XROWB) // ~52.3 MB
#define WQ_OFF 131072

typedef short bf16x8 __attribute__((ext_vector_type(8)));
typedef float f32x4 __attribute__((ext_vector_type(4)));
typedef unsigned int u32;

#define GLOAD_LDS(g, l, sz)                                                   \
    __builtin_amdgcn_global_load_lds(                                         \
        (const __attribute__((address_space(1))) u32*)(const void*)(g),       \
        (__attribute__((address_space(3))) u32*)(void*)(l), (sz), 0, 0)

__device__ inline unsigned short f2bf(float f) {
    union { float f; unsigned u; } v;
    v.f = f;
    unsigned u = v.u;
    u += 0x7fffu + ((u >> 16) & 1u);   // RNE
    return (unsigned short)(u >> 16);
}

// ---------------------------------------------------------------------------
// Transform (VERIFIED r4/r6/r9, HBM floor): x[b][c][h][w] fp32 ->
// xt[b][h][slot][cin] bf16; dword for cin-pair cp at (cp*4)^((slot&7)<<4)
// inside each 128-B chunk.
// Blocks 0..17 additionally pre-pack quantized weights into wq2:
// wq2[mw][t][lane] 16-B entries, t=(shift*2+c0)*2+m, matching the conv
// K-loop's A-fragment consumption order. Tile loads are 1-KB coalesced.
// ---------------------------------------------------------------------------
__global__ __launch_bounds__(256) void xform(const float* __restrict__ x,
                                             unsigned short* __restrict__ xt,
                                             const float* __restrict__ w,
                                             unsigned short* __restrict__ wq2) {
    __shared__ unsigned short pl[C_ * SLOTS];

    const int tid = threadIdx.x;
    const int b   = blockIdx.x / H_;
    const int h   = blockIdx.x % H_;

#pragma unroll
    for (int it = 0; it < 7; ++it) {
        const int u  = tid + 256 * it;        // < 1792 = 64c * 28 quads
        const int c  = u / 28;
        const int w4 = u % 28;
        const f32x4 v =
            *(const f32x4*)(x + ((size_t)(b * C_ + c) * H_ + h) * W_ + w4 * 4);
        const u32 lo = (u32)f2bf(v[0]) | ((u32)f2bf(v[1]) << 16);
        const u32 hi = (u32)f2bf(v[2]) | ((u32)f2bf(v[3]) << 16);
        u32* p = (u32*)&pl[c * SLOTS + w4 * 4];
        p[0] = lo;
        p[1] = hi;
    }
    __syncthreads();

    unsigned short* xtrow = xt + (size_t)(b * H_ + h) * (XROWB / 2);
#pragma unroll
    for (int it = 0; it < 15; ++it) {
        const int u = tid + 256 * it;         // < 3648 = 114 slots * 32 cps
        if (u < SLOTS * 32) {
            const int slot = u >> 5;
            const int cp   = u & 31;
            u32 val = 0;
            if (1 <= slot && slot <= 112) {
                const int ww = slot - 1;
                val = (u32)pl[(2 * cp) * SLOTS + ww] |
                      ((u32)pl[(2 * cp + 1) * SLOTS + ww] << 16);
            }
            *(u32*)((char*)xtrow + slot * CHUNK +
                    ((cp * 4) ^ ((slot & 7) << 4))) = val;
        }
    }

    // ---- folded weight quantize + per-wave prepack (4608 threads) ----
    if (blockIdx.x < 18) {
        const int i = blockIdx.x * 256 + tid;   // < 4608 = 2*36*64
        const int lane = i & 63;
        const int t    = (i >> 6) % 36;
        const int mw   = i / 2304;
        const int shift = t >> 2;
        const int c0    = (t >> 1) & 1;
        const int m     = t & 1;
        const int dh = shift / 3, dw = shift % 3;
        const int lcol = lane & 15, kg = lane >> 4;
        const int cout = mw * 32 + m * 16 + lcol;
        const int cinb = c0 * 32 + kg * 8;
        unsigned short pk[8];
#pragma unroll
        for (int j = 0; j < 8; ++j) {
            const float v = w[((cout * C_ + cinb + j) * 3 + dh) * 3 + dw];
            pk[j] = (v > 0.f) ? (unsigned short)0x3F80
                              : ((v < 0.f) ? (unsigned short)0xBF80
                                           : (unsigned short)0);
        }
        bf16x8 pv;
#pragma unroll
        for (int j = 0; j < 8; ++j) pv[j] = (short)pk[j];
        *(bf16x8*)((char*)wq2 + ((size_t)(mw * 36 + t) * 64 + lane) * 16) = pv;
    }
}

// ---------------------------------------------------------------------------
// Conv implicit GEMM = round-4 structure with REGISTER-RESIDENT weights.
// Block = (b, 2 output rows); waves 2x2 (mw: cout half, nw: row).
// Wave preloads its 36 A-tiles (576 B/lane = 144 VGPRs) from wq2 before the
// barrier; the K-loop is then pure {ds_read_b128 -> 2 MFMA} with ZERO global
// loads on the critical path (r6/r9 lesson). launch_bounds(256,2): 256 VGPRs.
// ---------------------------------------------------------------------------
__global__ __launch_bounds__(256, 2) void conv_mfma(
    const unsigned short* __restrict__ xt, const unsigned short* __restrict__ wq2,
    const float* __restrict__ bias, const float* __restrict__ scale,
    float* __restrict__ out) {
    __shared__ char xs[4 * XROWB];   // 58368 B -> 2 blocks/CU

    const int tid  = threadIdx.x;
    const int lane = tid & 63;
    const int wave = tid >> 6;
    const int lcol = lane & 15;
    const int kg   = lane >> 4;
    const int mw   = wave >> 1;      // cout half
    const int nw   = wave & 1;       // row within tile

    const int bid = blockIdx.x;
    const int s   = (bid & 7) * (NBLKC / 8) + (bid >> 3);   // XCD-bijective
    const int b   = s / HTILES;
    const int h0  = (s % HTILES) * 2;

    const char* xtc = (const char*)xt + (size_t)b * H_ * XROWB;

    // ---- preload all 36 weight tiles for this wave (coalesced, L2) ----
    bf16x8 wt[36];
    {
        const char* wp = (const char*)wq2 + (size_t)mw * 36 * 1024 + lane * 16;
#pragma unroll
        for (int t = 0; t < 36; ++t) wt[t] = *(const bf16x8*)(wp + t * 1024);
    }

    // ---- stage: wave r copies xt row h0-1+r linearly into LDS ----
    {
        const int r    = wave;
        const int xrow = h0 - 1 + r;
        char* dst = xs + r * XROWB;
        if (0 <= xrow && xrow < H_) {
            const char* src = xtc + (size_t)xrow * XROWB + lane * 16;
#pragma unroll
            for (int ch = 0; ch < 14; ++ch)
                GLOAD_LDS(src + ch * 1024, dst + ch * 1024, 16);
            GLOAD_LDS(xtc + (size_t)xrow * XROWB + 14336 + lane * 4,
                      dst + 14336, 4);
        } else {
            char* d = dst + lane * 16;
            const f32x4 z = {0.f, 0.f, 0.f, 0.f};
#pragma unroll
            for (int ch = 0; ch < 14; ++ch) *(f32x4*)(d + ch * 1024) = z;
            *(u32*)(dst + 14336 + lane * 4) = 0u;
        }
    }
    __syncthreads();

    // swizzle-adjusted K-offsets (verified r4)
    int koff[3][2];
#pragma unroll
    for (int dw = 0; dw < 3; ++dw) {
        const int key = ((lcol + dw) & 7) << 4;
        koff[dw][0] = (kg * 16) ^ key;
        koff[dw][1] = (64 + kg * 16) ^ key;
    }

    f32x4 acc[2][7];
#pragma unroll
    for (int m = 0; m < 2; ++m)
#pragma unroll
        for (int nf = 0; nf < 7; ++nf) acc[m][nf] = (f32x4){0.f, 0.f, 0.f, 0.f};

#pragma unroll
    for (int dh = 0; dh < 3; ++dh) {
        const char* rowb = xs + (nw + dh) * XROWB;
#pragma unroll
        for (int dw = 0; dw < 3; ++dw) {
            const char* colb = rowb + (lcol + dw) * CHUNK;
#pragma unroll
            for (int c0 = 0; c0 < 2; ++c0) {
                const int t0 = ((dh * 3 + dw) * 2 + c0) * 2;   // wt index
                const char* cb = colb + koff[dw][c0];
#pragma unroll
                for (int nf = 0; nf < 7; ++nf) {
                    const bf16x8 bv = *(const bf16x8*)(cb + nf * 2048);
                    acc[0][nf] = __builtin_amdgcn_mfma_f32_16x16x32_bf16(
                        wt[t0 + 0], bv, acc[0][nf], 0, 0, 0);
                    acc[1][nf] = __builtin_amdgcn_mfma_f32_16x16x32_bf16(
                        wt[t0 + 1], bv, acc[1][nf], 0, 0, 0);
                }
            }
        }
    }

    // ---- epilogue ----
    const float sc = scale[0];
    const int h = h0 + nw;
#pragma unroll
    for (int m = 0; m < 2; ++m) {
        const int cobase = mw * 32 + m * 16 + kg * 4;
        const f32x4 bs = *(const f32x4*)(bias + cobase);
#pragma unroll
        for (int nf = 0; nf < 7; ++nf) {
            const int col = nf * 16 + lcol;
#pragma unroll
            for (int rr = 0; rr < 4; ++rr)
                out[((size_t)(b * C_ + cobase + rr)) * HW + h * W_ + col] =
                    sc * (acc[m][nf][rr] + bs[rr]);
        }
    }
}

extern "C" void kernel_launch(void* const* d_in, const int* in_sizes, int n_in,
                              void* d_out, int out_size, void* d_ws,
                              size_t ws_size, hipStream_t stream) {
    const float* x     = (const float*)d_in[0];
    const float* w     = (const float*)d_in[1];
    const float* bias  = (const float*)d_in[2];
    const float* scale = (const float*)d_in[3];
    float* out         = (float*)d_out;

    unsigned short* wq2 = (unsigned short*)d_ws;  // 73728 B prepacked weights
    unsigned short* xt  = (unsigned short*)((char*)d_ws + WQ_OFF);

    xform<<<B_ * H_, 256, 0, stream>>>(x, xt, w, wq2);
    conv_mfma<<<NBLKC, 256, 0, stream>>>(xt, wq2, bias, scale, out);
}